// Round 2
// baseline (1036.682 us; speedup 1.0000x reference)
//
#include <hip/hip_runtime.h>

#define B_ 512
#define Q_ 32768
#define D_ 256
#define L_ 32769  // 1 + Q

#define BM 128
#define BN 128
// BK = 64 bf16 (128 B per LDS row = 8 chunks of 16 B)

typedef __attribute__((ext_vector_type(8))) short short8;
typedef __attribute__((ext_vector_type(4))) float f32x4;

// round-to-nearest-even fp32 -> bf16 bits (truncation would bias dot by ~2^-8 and FAIL accuracy)
__device__ __forceinline__ unsigned int f2bf1(float f) {
    unsigned int u = __float_as_uint(f);
    return (u + 0x7FFFu + ((u >> 16) & 1u)) >> 16;
}
__device__ __forceinline__ unsigned int f2bf2(float lo, float hi) {
    return f2bf1(lo) | (f2bf1(hi) << 16);
}

// async global->LDS, 16 B per lane; LDS dest must be wave-uniform base (+lane*16 implicit)
#define GLOAD_LDS16(ldsptr, gptr)                                              \
    __builtin_amdgcn_global_load_lds(                                          \
        (const __attribute__((address_space(1))) unsigned int*)(gptr),         \
        (__attribute__((address_space(3))) unsigned int*)(ldsptr), 16, 0, 0)

// ---------------- cvt: fp32 -> bf16 (RNE) for mem[4] and x[4], into scratch ----------------
__global__ void cvt_kernel(const float* __restrict__ m0, const float* __restrict__ m1,
                           const float* __restrict__ m2, const float* __restrict__ m3,
                           const float* __restrict__ x0, const float* __restrict__ x1,
                           const float* __restrict__ x2, const float* __restrict__ x3,
                           unsigned short* __restrict__ mem_bf,
                           unsigned short* __restrict__ x_bf) {
    const int MEMU = 4 << 20;   // 4 views * 2^23 elems / 8-per-unit
    const int XU = 4 << 14;     // 4 views * 131072 elems / 8-per-unit
    for (int u = blockIdx.x * blockDim.x + threadIdx.x; u < MEMU + XU;
         u += gridDim.x * blockDim.x) {
        const float* s;
        unsigned short* d;
        if (u < MEMU) {
            int v = u >> 20;
            int rem = u & ((1 << 20) - 1);
            const float* mv = (v == 0) ? m0 : (v == 1) ? m1 : (v == 2) ? m2 : m3;
            s = mv + (size_t)rem * 8;
            d = mem_bf + ((size_t)v << 23) + (size_t)rem * 8;
        } else {
            int u2 = u - MEMU;
            int v = u2 >> 14;
            int rem = u2 & 16383;
            const float* xv = (v == 0) ? x0 : (v == 1) ? x1 : (v == 2) ? x2 : x3;
            s = xv + rem * 8;
            d = x_bf + v * 131072 + rem * 8;
        }
        float4 a = ((const float4*)s)[0];
        float4 b = ((const float4*)s)[1];
        uint4 o;
        o.x = f2bf2(a.x, a.y);
        o.y = f2bf2(a.z, a.w);
        o.z = f2bf2(b.x, b.y);
        o.w = f2bf2(b.z, b.w);
        *(uint4*)d = o;
    }
}

// ---------------- prep: per-row norms -> scales, and the self-dot column (fp32 exact) ----------------
__global__ void prep_kernel(const float* __restrict__ x0, const float* __restrict__ x1,
                            const float* __restrict__ x2, const float* __restrict__ x3,
                            float* __restrict__ out0, float* __restrict__ scales) {
    const int ci[8] = {0, 0, 0, 1, 1, 2, 2, 3};
    const int cj[8] = {1, 2, 3, 0, 2, 0, 1, 0};
    const float* xs[4] = {x0, x1, x2, x3};
    int c = blockIdx.x;
    const float* xi = xs[ci[c]];
    const float* xj = xs[cj[c]];
    int wave = threadIdx.x >> 6;
    int lane = threadIdx.x & 63;

    for (int b = wave; b < B_; b += 4) {
        float4 a = ((const float4*)(xi + b * D_))[lane];
        float4 bb = ((const float4*)(xj + b * D_))[lane];
        float dot = a.x * bb.x + a.y * bb.y + a.z * bb.z + a.w * bb.w;
        float ni = a.x * a.x + a.y * a.y + a.z * a.z + a.w * a.w;
        float nj = bb.x * bb.x + bb.y * bb.y + bb.z * bb.z + bb.w * bb.w;
        for (int off = 32; off; off >>= 1) {
            dot += __shfl_down(dot, off);
            ni  += __shfl_down(ni, off);
            nj  += __shfl_down(nj, off);
        }
        if (lane == 0) {
            float s = 1.0f / (sqrtf(ni) * sqrtf(nj) * 0.07f);
            scales[c * B_ + b] = s;
            out0[(size_t)(c * B_ + b) * L_] = __expf(dot * s);
        }
    }
}

// ---------------- GEMM: out0[c][b][1+q] = exp(<x_i[b], mem_j[q]> * scale[c][b]) ----------------
// bf16 inputs pre-converted; staging via global_load_lds w=16 with chunk-XOR swizzle
// (swizzle applied on the GLOBAL source address, LDS dest stays linear — m173 pattern).
// 1-D grid of 8192 blocks with bijective XCD remap: XCD x owns combo c == x,
// so each combo's A panel (256 KB) is L2-resident and B panels are shared in-L2
// by the 4 adjacent M-blocks. Pure index bijection — mapping only affects speed.
__global__ __launch_bounds__(256) void gemm_kernel(
    const unsigned short* __restrict__ x_bf,
    const unsigned short* __restrict__ mem_bf,
    const float* __restrict__ scales, float* __restrict__ out0) {
    const int ci[8] = {0, 0, 0, 1, 1, 2, 2, 3};
    const int cj[8] = {1, 2, 3, 0, 2, 0, 1, 0};

    // remap: HW round-robins linear id over 8 XCDs; give XCD (bid&7) the
    // contiguous chunk [x*1024, (x+1)*1024) => c = bid&7, bijective (8192 % 8 == 0)
    const int bid = blockIdx.x;
    const int nl = (bid & 7) * 1024 + (bid >> 3);
    const int m0 = (nl & 3) * BM;          // M-blocks innermost: 4 share a B panel
    const int n0 = ((nl >> 2) & 255) * BN;
    const int c = nl >> 10;

    const unsigned short* A = x_bf + ci[c] * (B_ * D_);
    const unsigned short* Bm = mem_bf + (size_t)cj[c] * ((size_t)Q_ * D_);

    __shared__ __align__(16) unsigned short As[BM * 64];  // 16 KB
    __shared__ __align__(16) unsigned short Bs[BN * 64];  // 16 KB

    const int tid = threadIdx.x;
    const int lane = tid & 63;
    const int wave = tid >> 6;
    const int wm = (wave & 1) * 64;
    const int wn = (wave >> 1) * 64;
    const int q4 = lane >> 4;
    const int l15 = lane & 15;

    // staging: thread t fills LDS linear slot (row = call*32 + t>>3, chunk16B = t&7);
    // swizzled content: global chunk = (t&7) ^ ((t>>3)&7)   [call*32 ≡ 0 mod 8]
    const int srow = tid >> 3;
    const int sc8 = (((tid & 7) ^ (srow & 7)) << 3);  // bf16 element offset within row
    const unsigned short* gA = A + (size_t)(m0 + srow) * D_ + sc8;
    const unsigned short* gB = Bm + (size_t)(n0 + srow) * D_ + sc8;
    char* ldsA = (char*)As + (wave << 10);  // wave-uniform base, +lane*16 implicit
    char* ldsB = (char*)Bs + (wave << 10);

    // ds_read byte offsets: row_f = wm+mt*16+l15, chunk = ks*4+q4, stored at chunk^(row_f&7)
    const int rbA = (wm + l15) * 128;
    const int rbB = (wn + l15) * 128;
    const int x7 = l15 & 7;
    const int co0 = ((q4 ^ x7) << 4);
    const int co1 = (((4 + q4) ^ x7) << 4);

    f32x4 acc[4][4];
    for (int mt = 0; mt < 4; mt++)
        for (int nt = 0; nt < 4; nt++)
            acc[mt][nt] = (f32x4){0.f, 0.f, 0.f, 0.f};

    for (int k0 = 0; k0 < D_; k0 += 64) {
        if (k0) __syncthreads();  // all waves done reading previous tiles
#pragma unroll
        for (int call = 0; call < 4; call++) {
            GLOAD_LDS16(ldsA + call * 4096, gA + k0 + call * (32 * D_));
            GLOAD_LDS16(ldsB + call * 4096, gB + k0 + call * (32 * D_));
        }
        __syncthreads();  // drains vmcnt(0): staged data visible

#pragma unroll
        for (int ks = 0; ks < 2; ks++) {
            const int co = ks ? co1 : co0;
            short8 af[4], bfr[4];
#pragma unroll
            for (int mt = 0; mt < 4; mt++)
                af[mt] = *(const short8*)((const char*)As + rbA + mt * 2048 + co);
#pragma unroll
            for (int nt = 0; nt < 4; nt++)
                bfr[nt] = *(const short8*)((const char*)Bs + rbB + nt * 2048 + co);
#pragma unroll
            for (int mt = 0; mt < 4; mt++)
#pragma unroll
                for (int nt = 0; nt < 4; nt++)
                    acc[mt][nt] = __builtin_amdgcn_mfma_f32_16x16x32_bf16(
                        af[mt], bfr[nt], acc[mt][nt], 0, 0, 0);
        }
    }

    // epilogue: C/D layout col = lane&15, row = (lane>>4)*4 + reg   [verified m89/m91]
    for (int mt = 0; mt < 4; mt++) {
        int gr = m0 + wm + mt * 16 + q4 * 4;
        float s0 = scales[c * B_ + gr + 0];
        float s1 = scales[c * B_ + gr + 1];
        float s2 = scales[c * B_ + gr + 2];
        float s3 = scales[c * B_ + gr + 3];
        size_t rowbase = (size_t)(c * B_ + gr) * L_ + 1;
        for (int nt = 0; nt < 4; nt++) {
            int gc = n0 + wn + nt * 16 + l15;
            f32x4 v = acc[mt][nt];
            out0[rowbase + gc]          = __expf(v.x * s0);
            out0[rowbase + L_ + gc]     = __expf(v.y * s1);
            out0[rowbase + 2 * L_ + gc] = __expf(v.z * s2);
            out0[rowbase + 3 * L_ + gc] = __expf(v.w * s3);
        }
    }
}

// ---------------- FIFO shift: new_mem[v] = concat(mem_v[512:], y_v) ----------------
__global__ void shift_kernel(const float4* __restrict__ mm0, const float4* __restrict__ mm1,
                             const float4* __restrict__ mm2, const float4* __restrict__ mm3,
                             const float4* __restrict__ yy0, const float4* __restrict__ yy1,
                             const float4* __restrict__ yy2, const float4* __restrict__ yy3,
                             float4* __restrict__ out1) {
    const float4* mems[4] = {mm0, mm1, mm2, mm3};
    const float4* ys[4] = {yy0, yy1, yy2, yy3};
    const int per_view = Q_ * D_ / 4;          // 2,097,152 float4
    const int boundary = (Q_ - B_) * D_ / 4;   // 2,064,384
    const int shift = B_ * D_ / 4;             // 32,768
    const int total = 4 * per_view;
    for (int idx = blockIdx.x * blockDim.x + threadIdx.x; idx < total;
         idx += gridDim.x * blockDim.x) {
        int v = idx >> 21;
        int rem = idx & (per_view - 1);
        float4 val = (rem < boundary) ? mems[v][rem + shift] : ys[v][rem - boundary];
        out1[idx] = val;
    }
}

extern "C" void kernel_launch(void* const* d_in, const int* in_sizes, int n_in,
                              void* d_out, int out_size, void* d_ws, size_t ws_size,
                              hipStream_t stream) {
    const float* x[4];
    const float* y[4];
    const float* mem[4];
    // setup_inputs() dict order: x0,y0,mem0, x1,y1,mem1, ... ; fall back to
    // signature order (x0..x3,y0..y3,mem0..3) if sizes say otherwise.
    bool dict_order = (n_in >= 3) && (in_sizes[2] == Q_ * D_);
    for (int v = 0; v < 4; v++) {
        if (dict_order) {
            x[v] = (const float*)d_in[3 * v];
            y[v] = (const float*)d_in[3 * v + 1];
            mem[v] = (const float*)d_in[3 * v + 2];
        } else {
            x[v] = (const float*)d_in[v];
            y[v] = (const float*)d_in[4 + v];
            mem[v] = (const float*)d_in[8 + v];
        }
    }
    float* out0 = (float*)d_out;
    float* out1 = out0 + (size_t)8 * B_ * L_;
    float* scales = (float*)d_ws;  // 8*512 floats = 16 KB

    // bf16 scratch lives in the out1 region (dead until shift_kernel, stream-ordered):
    // mem_bf = 4*Q*D bf16 = 67.1 MB, x_bf = 4*B*D bf16 = 1 MB; out1 region is 134.2 MB.
    unsigned short* mem_bf = (unsigned short*)out1;
    unsigned short* x_bf = mem_bf + (size_t)4 * Q_ * D_;

    cvt_kernel<<<2048, 256, 0, stream>>>(mem[0], mem[1], mem[2], mem[3],
                                         x[0], x[1], x[2], x[3], mem_bf, x_bf);

    prep_kernel<<<8, 256, 0, stream>>>(x[0], x[1], x[2], x[3], out0, scales);

    gemm_kernel<<<8192, 256, 0, stream>>>(x_bf, mem_bf, scales, out0);

    shift_kernel<<<4096, 256, 0, stream>>>(
        (const float4*)mem[0], (const float4*)mem[1], (const float4*)mem[2], (const float4*)mem[3],
        (const float4*)y[0], (const float4*)y[1], (const float4*)y[2], (const float4*)y[3],
        (float4*)out1);
}

// Round 4
// 1021.570 us; speedup vs baseline: 1.0148x; 1.0148x over previous
//
#include <hip/hip_runtime.h>

#define B_ 512
#define Q_ 32768
#define D_ 256
#define L_ 32769  // 1 + Q

#define BM 128
#define BN 128
// BK = 64 bf16 (128 B per LDS row = 8 chunks of 16 B)

typedef __attribute__((ext_vector_type(8))) short short8;
typedef __attribute__((ext_vector_type(4))) float f32x4;

// round-to-nearest-even fp32 -> bf16 bits (truncation would bias dot by ~2^-8 and FAIL accuracy)
__device__ __forceinline__ unsigned int f2bf1(float f) {
    unsigned int u = __float_as_uint(f);
    return (u + 0x7FFFu + ((u >> 16) & 1u)) >> 16;
}
__device__ __forceinline__ unsigned int f2bf2(float lo, float hi) {
    return f2bf1(lo) | (f2bf1(hi) << 16);
}

// async global->LDS, 16 B per lane; LDS dest must be wave-uniform base (+lane*16 implicit)
#define GLOAD_LDS16(ldsptr, gptr)                                              \
    __builtin_amdgcn_global_load_lds(                                          \
        (const __attribute__((address_space(1))) unsigned int*)(gptr),         \
        (__attribute__((address_space(3))) unsigned int*)(ldsptr), 16, 0, 0)

// ---------------- cvt: fp32 -> bf16 (RNE) for mem[4] and x[4], into scratch ----------------
__global__ void cvt_kernel(const float* __restrict__ m0, const float* __restrict__ m1,
                           const float* __restrict__ m2, const float* __restrict__ m3,
                           const float* __restrict__ x0, const float* __restrict__ x1,
                           const float* __restrict__ x2, const float* __restrict__ x3,
                           unsigned short* __restrict__ mem_bf,
                           unsigned short* __restrict__ x_bf) {
    const int MEMU = 4 << 20;   // 4 views * 2^23 elems / 8-per-unit
    const int XU = 4 << 14;     // 4 views * 131072 elems / 8-per-unit
    for (int u = blockIdx.x * blockDim.x + threadIdx.x; u < MEMU + XU;
         u += gridDim.x * blockDim.x) {
        const float* s;
        unsigned short* d;
        if (u < MEMU) {
            int v = u >> 20;
            int rem = u & ((1 << 20) - 1);
            const float* mv = (v == 0) ? m0 : (v == 1) ? m1 : (v == 2) ? m2 : m3;
            s = mv + (size_t)rem * 8;
            d = mem_bf + ((size_t)v << 23) + (size_t)rem * 8;
        } else {
            int u2 = u - MEMU;
            int v = u2 >> 14;
            int rem = u2 & 16383;
            const float* xv = (v == 0) ? x0 : (v == 1) ? x1 : (v == 2) ? x2 : x3;
            s = xv + rem * 8;
            d = x_bf + v * 131072 + rem * 8;
        }
        float4 a = ((const float4*)s)[0];
        float4 b = ((const float4*)s)[1];
        uint4 o;
        o.x = f2bf2(a.x, a.y);
        o.y = f2bf2(a.z, a.w);
        o.z = f2bf2(b.x, b.y);
        o.w = f2bf2(b.z, b.w);
        *(uint4*)d = o;
    }
}

// ---------------- prep: per-row norms -> scales, and the self-dot column (fp32 exact) ----------------
// 256 blocks (32 per combo, 16 rows each) — the old 8-block version used 8 of 256 CUs
// and serialized ~40-60 us of work that takes ~4 us when spread.
__global__ void prep_kernel(const float* __restrict__ x0, const float* __restrict__ x1,
                            const float* __restrict__ x2, const float* __restrict__ x3,
                            float* __restrict__ out0, float* __restrict__ scales) {
    const int ci[8] = {0, 0, 0, 1, 1, 2, 2, 3};
    const int cj[8] = {1, 2, 3, 0, 2, 0, 1, 0};
    const float* xs[4] = {x0, x1, x2, x3};
    const int c = blockIdx.x >> 5;
    const int base = (blockIdx.x & 31) * 16;
    const float* xi = xs[ci[c]];
    const float* xj = xs[cj[c]];
    int wave = threadIdx.x >> 6;
    int lane = threadIdx.x & 63;

    for (int b = base + wave; b < base + 16; b += 4) {
        float4 a = ((const float4*)(xi + b * D_))[lane];
        float4 bb = ((const float4*)(xj + b * D_))[lane];
        float dot = a.x * bb.x + a.y * bb.y + a.z * bb.z + a.w * bb.w;
        float ni = a.x * a.x + a.y * a.y + a.z * a.z + a.w * a.w;
        float nj = bb.x * bb.x + bb.y * bb.y + bb.z * bb.z + bb.w * bb.w;
        for (int off = 32; off; off >>= 1) {
            dot += __shfl_down(dot, off);
            ni  += __shfl_down(ni, off);
            nj  += __shfl_down(nj, off);
        }
        if (lane == 0) {
            float s = 1.0f / (sqrtf(ni) * sqrtf(nj) * 0.07f);
            scales[c * B_ + b] = s;
            out0[(size_t)(c * B_ + b) * L_] = __expf(dot * s);
        }
    }
}

// ---------------- GEMM: out0[c][b][1+q] = exp(<x_i[b], mem_j[q]> * scale[c][b]) ----------------
// bf16 inputs pre-converted; staging via global_load_lds w=16 with chunk-XOR swizzle
// (swizzle applied on the GLOBAL source address, LDS dest stays linear — m173 pattern).
// 1-D grid of 8192 blocks with bijective XCD remap: XCD x owns combo c == x,
// so each combo's A panel (256 KB) is L2-resident and B panels are shared in-L2
// by the 4 adjacent M-blocks. Pure index bijection — mapping only affects speed.
// __launch_bounds__(256,4): 4 blocks/CU (VGPR<=128; K-loop live set ~110 regs, no spill)
// — K=256 gives only 4 K-steps, so staging latency must be hidden by occupancy.
__global__ __launch_bounds__(256, 4) void gemm_kernel(
    const unsigned short* __restrict__ x_bf,
    const unsigned short* __restrict__ mem_bf,
    const float* __restrict__ scales, float* __restrict__ out0) {
    const int ci[8] = {0, 0, 0, 1, 1, 2, 2, 3};
    const int cj[8] = {1, 2, 3, 0, 2, 0, 1, 0};

    // remap: HW round-robins linear id over 8 XCDs; give XCD (bid&7) the
    // contiguous chunk [x*1024, (x+1)*1024) => c = bid&7, bijective (8192 % 8 == 0)
    const int bid = blockIdx.x;
    const int nl = (bid & 7) * 1024 + (bid >> 3);
    const int m0 = (nl & 3) * BM;          // M-blocks innermost: 4 share a B panel
    const int n0 = ((nl >> 2) & 255) * BN;
    const int c = nl >> 10;

    const unsigned short* A = x_bf + ci[c] * (B_ * D_);
    const unsigned short* Bm = mem_bf + (size_t)cj[c] * ((size_t)Q_ * D_);

    __shared__ __align__(16) unsigned short As[BM * 64];  // 16 KB
    __shared__ __align__(16) unsigned short Bs[BN * 64];  // 16 KB

    const int tid = threadIdx.x;
    const int lane = tid & 63;
    const int wave = tid >> 6;
    const int wm = (wave & 1) * 64;
    const int wn = (wave >> 1) * 64;
    const int q4 = lane >> 4;
    const int l15 = lane & 15;

    // staging: thread t fills LDS linear slot (row = call*32 + t>>3, chunk16B = t&7);
    // swizzled content: global chunk = (t&7) ^ ((t>>3)&7)   [call*32 ≡ 0 mod 8]
    const int srow = tid >> 3;
    const int sc8 = (((tid & 7) ^ (srow & 7)) << 3);  // bf16 element offset within row
    const unsigned short* gA = A + (size_t)(m0 + srow) * D_ + sc8;
    const unsigned short* gB = Bm + (size_t)(n0 + srow) * D_ + sc8;
    char* ldsA = (char*)As + (wave << 10);  // wave-uniform base, +lane*16 implicit
    char* ldsB = (char*)Bs + (wave << 10);

    // ds_read byte offsets: row_f = wm+mt*16+l15, chunk = ks*4+q4, stored at chunk^(row_f&7)
    const int rbA = (wm + l15) * 128;
    const int rbB = (wn + l15) * 128;
    const int x7 = l15 & 7;
    const int co0 = ((q4 ^ x7) << 4);
    const int co1 = (((4 + q4) ^ x7) << 4);

    f32x4 acc[4][4];
    for (int mt = 0; mt < 4; mt++)
        for (int nt = 0; nt < 4; nt++)
            acc[mt][nt] = (f32x4){0.f, 0.f, 0.f, 0.f};

    for (int k0 = 0; k0 < D_; k0 += 64) {
        if (k0) __syncthreads();  // all waves done reading previous tiles
#pragma unroll
        for (int call = 0; call < 4; call++) {
            GLOAD_LDS16(ldsA + call * 4096, gA + k0 + call * (32 * D_));
            GLOAD_LDS16(ldsB + call * 4096, gB + k0 + call * (32 * D_));
        }
        __syncthreads();  // drains vmcnt(0): staged data visible

#pragma unroll
        for (int ks = 0; ks < 2; ks++) {
            const int co = ks ? co1 : co0;
            short8 af[4], bfr[4];
#pragma unroll
            for (int mt = 0; mt < 4; mt++)
                af[mt] = *(const short8*)((const char*)As + rbA + mt * 2048 + co);
#pragma unroll
            for (int nt = 0; nt < 4; nt++)
                bfr[nt] = *(const short8*)((const char*)Bs + rbB + nt * 2048 + co);
#pragma unroll
            for (int mt = 0; mt < 4; mt++)
#pragma unroll
                for (int nt = 0; nt < 4; nt++)
                    acc[mt][nt] = __builtin_amdgcn_mfma_f32_16x16x32_bf16(
                        af[mt], bfr[nt], acc[mt][nt], 0, 0, 0);
        }
    }

    // epilogue: C/D layout col = lane&15, row = (lane>>4)*4 + reg   [verified m89/m91]
    for (int mt = 0; mt < 4; mt++) {
        int gr = m0 + wm + mt * 16 + q4 * 4;
        float s0 = scales[c * B_ + gr + 0];
        float s1 = scales[c * B_ + gr + 1];
        float s2 = scales[c * B_ + gr + 2];
        float s3 = scales[c * B_ + gr + 3];
        size_t rowbase = (size_t)(c * B_ + gr) * L_ + 1;
        for (int nt = 0; nt < 4; nt++) {
            int gc = n0 + wn + nt * 16 + l15;
            f32x4 v = acc[mt][nt];
            out0[rowbase + gc]          = __expf(v.x * s0);
            out0[rowbase + L_ + gc]     = __expf(v.y * s1);
            out0[rowbase + 2 * L_ + gc] = __expf(v.z * s2);
            out0[rowbase + 3 * L_ + gc] = __expf(v.w * s3);
        }
    }
}

// ---------------- FIFO shift: new_mem[v] = concat(mem_v[512:], y_v) ----------------
__global__ void shift_kernel(const float4* __restrict__ mm0, const float4* __restrict__ mm1,
                             const float4* __restrict__ mm2, const float4* __restrict__ mm3,
                             const float4* __restrict__ yy0, const float4* __restrict__ yy1,
                             const float4* __restrict__ yy2, const float4* __restrict__ yy3,
                             float4* __restrict__ out1) {
    const float4* mems[4] = {mm0, mm1, mm2, mm3};
    const float4* ys[4] = {yy0, yy1, yy2, yy3};
    const int per_view = Q_ * D_ / 4;          // 2,097,152 float4
    const int boundary = (Q_ - B_) * D_ / 4;   // 2,064,384
    const int shift = B_ * D_ / 4;             // 32,768
    const int total = 4 * per_view;
    for (int idx = blockIdx.x * blockDim.x + threadIdx.x; idx < total;
         idx += gridDim.x * blockDim.x) {
        int v = idx >> 21;
        int rem = idx & (per_view - 1);
        float4 val = (rem < boundary) ? mems[v][rem + shift] : ys[v][rem - boundary];
        out1[idx] = val;
    }
}

extern "C" void kernel_launch(void* const* d_in, const int* in_sizes, int n_in,
                              void* d_out, int out_size, void* d_ws, size_t ws_size,
                              hipStream_t stream) {
    const float* x[4];
    const float* y[4];
    const float* mem[4];
    // setup_inputs() dict order: x0,y0,mem0, x1,y1,mem1, ... ; fall back to
    // signature order (x0..x3,y0..y3,mem0..3) if sizes say otherwise.
    bool dict_order = (n_in >= 3) && (in_sizes[2] == Q_ * D_);
    for (int v = 0; v < 4; v++) {
        if (dict_order) {
            x[v] = (const float*)d_in[3 * v];
            y[v] = (const float*)d_in[3 * v + 1];
            mem[v] = (const float*)d_in[3 * v + 2];
        } else {
            x[v] = (const float*)d_in[v];
            y[v] = (const float*)d_in[4 + v];
            mem[v] = (const float*)d_in[8 + v];
        }
    }
    float* out0 = (float*)d_out;
    float* out1 = out0 + (size_t)8 * B_ * L_;
    float* scales = (float*)d_ws;  // 8*512 floats = 16 KB

    // bf16 scratch lives in the out1 region (dead until shift_kernel, stream-ordered):
    // mem_bf = 4*Q*D bf16 = 67.1 MB, x_bf = 4*B*D bf16 = 1 MB; out1 region is 134.2 MB.
    unsigned short* mem_bf = (unsigned short*)out1;
    unsigned short* x_bf = mem_bf + (size_t)4 * Q_ * D_;

    cvt_kernel<<<4096, 256, 0, stream>>>(mem[0], mem[1], mem[2], mem[3],
                                         x[0], x[1], x[2], x[3], mem_bf, x_bf);

    prep_kernel<<<256, 256, 0, stream>>>(x[0], x[1], x[2], x[3], out0, scales);

    gemm_kernel<<<8192, 256, 0, stream>>>(x_bf, mem_bf, scales, out0);

    shift_kernel<<<4096, 256, 0, stream>>>(
        (const float4*)mem[0], (const float4*)mem[1], (const float4*)mem[2], (const float4*)mem[3],
        (const float4*)y[0], (const float4*)y[1], (const float4*)y[2], (const float4*)y[3],
        (float4*)out1);
}